// Round 10
// baseline (459.012 us; speedup 1.0000x reference)
//
#include <hip/hip_runtime.h>

typedef _Float16 f16;
typedef _Float16 f16x4 __attribute__((ext_vector_type(4)));
typedef _Float16 f16x8 __attribute__((ext_vector_type(8)));
typedef float f32x4 __attribute__((ext_vector_type(4)));
typedef float f32x16 __attribute__((ext_vector_type(16)));

#define MFMA16(a, b, c) __builtin_amdgcn_mfma_f32_16x16x32_f16(a, b, c, 0, 0, 0)
#define MFMA32(a, b, c) __builtin_amdgcn_mfma_f32_32x32x16_f16(a, b, c, 0, 0, 0)

// ---------------- Kernel 1: per-(tensor,b,c) mean / inv-std ----------------
__global__ __launch_bounds__(256) void stats_kernel(
    const float* __restrict__ content, const float* __restrict__ style,
    float* __restrict__ mu, float* __restrict__ rs)
{
    int bid = blockIdx.x;            // tensor*2048 + b*512 + c
    int tensor = bid >> 11;
    int row = bid & 2047;
    const float* src = (tensor ? style : content) + (size_t)row * 4096;
    int t = threadIdx.x;
    float s = 0.f, ss = 0.f;
    for (int i = t; i < 1024; i += 256) {
        float4 v = reinterpret_cast<const float4*>(src)[i];
        s  += v.x + v.y + v.z + v.w;
        ss += v.x * v.x + v.y * v.y + v.z * v.z + v.w * v.w;
    }
    for (int off = 32; off > 0; off >>= 1) {
        s  += __shfl_down(s, off);
        ss += __shfl_down(ss, off);
    }
    __shared__ float sb[4], ssb[4];
    int wv = t >> 6;
    if ((t & 63) == 0) { sb[wv] = s; ssb[wv] = ss; }
    __syncthreads();
    if (t == 0) {
        float S  = sb[0] + sb[1] + sb[2] + sb[3];
        float SS = ssb[0] + ssb[1] + ssb[2] + ssb[3];
        float m  = S * (1.f / 4096.f);
        float var = (SS - 4096.f * m * m) * (1.f / 4095.f);
        mu[bid] = m;
        rs[bid] = rsqrtf(var + 1e-5f);
    }
}

// ---------------- Kernel 1b: W -> f16 one-shot conversion ------------------
__global__ __launch_bounds__(256) void wcvt_kernel(
    const float* __restrict__ Wq, const float* __restrict__ Wk,
    const float* __restrict__ Wv, f16* __restrict__ Wh)
{
    int p = blockIdx.y;
    const float* W = (p == 0 ? Wq : (p == 1 ? Wk : Wv));
    f16* dst = Wh + (size_t)p * 262144;
    int base = blockIdx.x * 256 + threadIdx.x;
#pragma unroll
    for (int i = 0; i < 8; ++i) {
        int e4 = i * 8192 + base;
        float4 v = reinterpret_cast<const float4*>(W)[e4];
        f16x4 pk;
        pk[0] = (f16)v.x; pk[1] = (f16)v.y; pk[2] = (f16)v.z; pk[3] = (f16)v.w;
        reinterpret_cast<f16x4*>(dst)[e4] = pk;
    }
}

// ---------------- Kernel 2: fused norm + 1x1-conv (Q,K,V), X-resident ------
__global__ __launch_bounds__(512, 3) void qkv_kernel(
    const float* __restrict__ content, const float* __restrict__ style,
    const f16* __restrict__ Wh,
    const float* __restrict__ bq, const float* __restrict__ bk,
    const float* __restrict__ bv,
    const float* __restrict__ mu, const float* __restrict__ rs,
    f16* __restrict__ Qt, f16* __restrict__ Kt, f16* __restrict__ Vc)
{
    int nb = blockIdx.x;
    int y  = blockIdx.y;
    int b = y / 3, p = y % 3;
    int n0 = nb * 64;
    const float* X    = (p == 0 ? content : style) + (size_t)b * 512 * 4096;
    const f16*   Wp   = Wh + (size_t)p * 262144;
    const float* bias = (p == 0 ? bq : (p == 1 ? bk : bv));
    const float* muT  = mu + (p == 0 ? 0 : 2048) + b * 512;
    const float* rsT  = rs + (p == 0 ? 0 : 2048) + b * 512;
    bool norm = (p < 2);

    __shared__ __align__(16) f16 Xt[64][520];

    int t = threadIdx.x;
    int lane = t & 63, w = t >> 6;
    int lg = lane >> 4, li = lane & 15;

#pragma unroll
    for (int i = 0; i < 16; ++i) {
        int c0 = i * 32 + w * 4;
        float x0 = X[(size_t)(c0 + 0) * 4096 + n0 + lane];
        float x1 = X[(size_t)(c0 + 1) * 4096 + n0 + lane];
        float x2 = X[(size_t)(c0 + 2) * 4096 + n0 + lane];
        float x3 = X[(size_t)(c0 + 3) * 4096 + n0 + lane];
        f16x4 pk;
        if (norm) {
            pk[0] = (f16)((x0 - muT[c0 + 0]) * rsT[c0 + 0]);
            pk[1] = (f16)((x1 - muT[c0 + 1]) * rsT[c0 + 1]);
            pk[2] = (f16)((x2 - muT[c0 + 2]) * rsT[c0 + 2]);
            pk[3] = (f16)((x3 - muT[c0 + 3]) * rsT[c0 + 3]);
        } else {
            pk[0] = (f16)x0; pk[1] = (f16)x1; pk[2] = (f16)x2; pk[3] = (f16)x3;
        }
        *reinterpret_cast<f16x4*>(&Xt[lane][c0]) = pk;
    }
    __syncthreads();

    f32x4 acc[4][4];
#pragma unroll
    for (int i = 0; i < 4; ++i)
#pragma unroll
        for (int j = 0; j < 4; ++j)
#pragma unroll
            for (int e = 0; e < 4; ++e) acc[i][j][e] = 0.f;

    const f16* wbase = Wp + (size_t)(w * 64 + li) * 512 + lg * 8;
    for (int kk = 0; kk < 16; ++kk) {
        f16x8 xf[4], wf[4];
#pragma unroll
        for (int jn = 0; jn < 4; ++jn)
            xf[jn] = *reinterpret_cast<const f16x8*>(&Xt[jn * 16 + li][kk * 32 + lg * 8]);
#pragma unroll
        for (int io = 0; io < 4; ++io)
            wf[io] = *reinterpret_cast<const f16x8*>(wbase + (size_t)io * 16 * 512 + kk * 32);
        if (p < 2) {
#pragma unroll
            for (int io = 0; io < 4; ++io)
#pragma unroll
                for (int jn = 0; jn < 4; ++jn)
                    acc[io][jn] = MFMA16(wf[io], xf[jn], acc[io][jn]);
        } else {
#pragma unroll
            for (int jn = 0; jn < 4; ++jn)
#pragma unroll
                for (int io = 0; io < 4; ++io)
                    acc[jn][io] = MFMA16(xf[jn], wf[io], acc[jn][io]);
        }
    }

    if (p < 2) {
        f16* dst = (p == 0 ? Qt : Kt) + (size_t)b * 4096 * 512;
#pragma unroll
        for (int io = 0; io < 4; ++io) {
            int ob = w * 64 + io * 16 + lg * 4;
            float4 bb = *reinterpret_cast<const float4*>(bias + ob);
#pragma unroll
            for (int jn = 0; jn < 4; ++jn) {
                int n = n0 + jn * 16 + li;
                f16x4 pk;
                pk[0] = (f16)(acc[io][jn][0] + bb.x);
                pk[1] = (f16)(acc[io][jn][1] + bb.y);
                pk[2] = (f16)(acc[io][jn][2] + bb.z);
                pk[3] = (f16)(acc[io][jn][3] + bb.w);
                *reinterpret_cast<f16x4*>(dst + (size_t)n * 512 + ob) = pk;
            }
        }
    } else {
#pragma unroll
        for (int io = 0; io < 4; ++io) {
            int o = w * 64 + io * 16 + li;
            float bb = bias[o];
            f16* dst = Vc + ((size_t)b * 512 + o) * 4096;
#pragma unroll
            for (int jn = 0; jn < 4; ++jn) {
                int n = n0 + jn * 16 + lg * 4;
                f16x4 pk;
#pragma unroll
                for (int e = 0; e < 4; ++e) pk[e] = (f16)(acc[jn][io][e] + bb);
                *reinterpret_cast<f16x4*>(dst + n) = pk;
            }
        }
    }
}

// ---------------- Kernel 3: flash attention, 10-wave, 32x32 QK -------------
// 640 thr = 2 QK waves (32 q-rows each, MFMA32, wave-local softmax) +
//           8 PV waves (c=64 each, MFMA16, V reg-double-buffered).
// TQ=64, KVBLK=64, grid 256, ONE barrier per iteration (65 total).
__global__ __launch_bounds__(640, 2) void attn_kernel(
    const f16* __restrict__ Qt, const f16* __restrict__ Kt,
    const f16* __restrict__ Vc, float* __restrict__ out)
{
    int bid = blockIdx.x;
    int orig = (bid & 7) * 32 + (bid >> 3);   // XCD chunking
    int b = orig >> 6;
    int n0 = (orig & 63) * 64;

    int t = threadIdx.x;
    int lane = t & 63, w = t >> 6;
    int lg = lane >> 4, li = lane & 15;
    int li32 = lane & 31, hi = lane >> 5;

    __shared__ __align__(16) f16 Km[2][64][528];   // K dbuf [m][c]
    __shared__ __align__(16) f16 Pl[2][64][68];    // P ping-pong [q][m]
    __shared__ __align__(16) float Rrow[2][64];
    __shared__ __align__(16) float Lrow[64];
    __shared__ int Rflag[2][2];

    const f16* Qb = Qt + (size_t)b * 4096 * 512;
    const f16* Kb = Kt + (size_t)b * 4096 * 512;
    const f16* Vb = Vc + (size_t)b * 512 * 4096;

    if (w < 2) {
        // ======== QK wave j = w: q-rows n0+j*32 .. +32, all 64 m ========
        int j = w;
        // Q B-frags (32x32x16): lane holds q=j*32+li32, k = kk*16 + hi*8 + e
        f16x8 qf[32];
#pragma unroll
        for (int kk = 0; kk < 32; ++kk)
            qf[kk] = *reinterpret_cast<const f16x8*>(
                Qb + (size_t)(n0 + j * 32 + li32) * 512 + kk * 16 + hi * 8);

#define STAGEK(TILE)                                                           \
        {                                                                      \
            int _db = (TILE) & 1;                                              \
            _Pragma("unroll")                                                  \
            for (int r = 0; r < 32; ++r) {                                     \
                const f16* _gs = Kb + ((size_t)(TILE) * 64 + j * 32 + r) * 512 \
                                 + lane * 8;                                   \
                __builtin_amdgcn_global_load_lds(                              \
                    (const __attribute__((address_space(1))) void*)_gs,        \
                    (__attribute__((address_space(3))) void*)&Km[_db][j * 32 + r][0], \
                    16, 0, 0);                                                 \
            }                                                                  \
        }

        STAGEK(0);
        float Mreg = -3.4e38f, Lreg = 0.f;
        __syncthreads();   // prologue: K0 staged

        for (int it = 0; it <= 64; ++it) {
            if (it <= 63) {
                int cur = it & 1;
                if (it < 63) STAGEK(it + 1);

                // S^T tiles: D[m][q], 4 independent 16-deep MFMA32 chains
                f32x16 s00, s01, s10, s11;
#pragma unroll
                for (int e = 0; e < 16; ++e) { s00[e] = 0.f; s01[e] = 0.f; s10[e] = 0.f; s11[e] = 0.f; }
                __builtin_amdgcn_s_setprio(1);
#pragma unroll
                for (int kk = 0; kk < 16; ++kk) {
                    f16x8 a0h0 = *reinterpret_cast<const f16x8*>(&Km[cur][li32][kk * 16 + hi * 8]);
                    f16x8 a0h1 = *reinterpret_cast<const f16x8*>(&Km[cur][li32][(kk + 16) * 16 + hi * 8]);
                    f16x8 a1h0 = *reinterpret_cast<const f16x8*>(&Km[cur][32 + li32][kk * 16 + hi * 8]);
                    f16x8 a1h1 = *reinterpret_cast<const f16x8*>(&Km[cur][32 + li32][(kk + 16) * 16 + hi * 8]);
                    s00 = MFMA32(a0h0, qf[kk], s00);
                    s01 = MFMA32(a0h1, qf[kk + 16], s01);
                    s10 = MFMA32(a1h0, qf[kk], s10);
                    s11 = MFMA32(a1h1, qf[kk + 16], s11);
                }
                __builtin_amdgcn_s_setprio(0);
                f32x16 st0, st1;
#pragma unroll
                for (int e = 0; e < 16; ++e) { st0[e] = s00[e] + s01[e]; st1[e] = s10[e] + s11[e]; }

                // wave-local softmax: lane has 32 m-vals for q=j*32+li32;
                // partner lane (^32) has the other 32 -> one shfl.
                float tm[16];
#pragma unroll
                for (int e = 0; e < 16; ++e) tm[e] = fmaxf(st0[e], st1[e]);
#pragma unroll
                for (int d = 8; d > 0; d >>= 1)
#pragma unroll
                    for (int e = 0; e < d; ++e) tm[e] = fmaxf(tm[e], tm[e + d]);
                float mx = fmaxf(tm[0], __shfl_xor(tm[0], 32));
                bool needR = (mx - Mreg) > 4.0f;       // defer-max THR=4
                float Mnew = needR ? mx : Mreg;
                float r = needR ? __expf(Mreg - Mnew) : 1.f;
                float p0[16], p1[16];
                float ts[16];
#pragma unroll
                for (int e = 0; e < 16; ++e) {
                    p0[e] = __expf(st0[e] - Mnew);
                    p1[e] = __expf(st1[e] - Mnew);
                    ts[e] = p0[e] + p1[e];
                }
#pragma unroll
                for (int d = 8; d > 0; d >>= 1)
#pragma unroll
                    for (int e = 0; e < d; ++e) ts[e] += ts[e + d];
                float sum = ts[0] + __shfl_xor(ts[0], 32);
                Lreg = Lreg * r + sum;
                Mreg = Mnew;

                // P write: m = mt*32 + 8g + 4hi + e  (D row formula)
#pragma unroll
                for (int g = 0; g < 4; ++g) {
                    f16x4 pk0, pk1;
#pragma unroll
                    for (int e = 0; e < 4; ++e) { pk0[e] = (f16)p0[g * 4 + e]; pk1[e] = (f16)p1[g * 4 + e]; }
                    *reinterpret_cast<f16x4*>(&Pl[cur][j * 32 + li32][g * 8 + hi * 4]) = pk0;
                    *reinterpret_cast<f16x4*>(&Pl[cur][j * 32 + li32][32 + g * 8 + hi * 4]) = pk1;
                }
                if (lane < 32) Rrow[cur][j * 32 + lane] = r;
                int any = __any(needR);
                if (lane == 0) Rflag[cur][j] = any;
                if (it == 63 && lane < 32) Lrow[j * 32 + lane] = Lreg;
            }
            __syncthreads();
        }
#undef STAGEK
    } else {
        // ======== PV wave (c-slice 64), V reg-double-buffered ========
        int pw = w - 2;
        int c0 = pw * 64;
        f32x4 acc[4][4];
#pragma unroll
        for (int fn = 0; fn < 4; ++fn)
#pragma unroll
            for (int fc = 0; fc < 4; ++fc)
#pragma unroll
                for (int e = 0; e < 4; ++e) acc[fn][fc][e] = 0.f;
        f16x8 vA[4][2], vB[4][2];

        __syncthreads();   // prologue barrier

#define PVBODY(IT, VCON, VLD)                                                  \
        {                                                                      \
            if ((IT) <= 63) {                                                  \
                const f16* vs = Vb + (size_t)(c0 + li) * 4096 + (IT) * 64 + lg * 8; \
                _Pragma("unroll")                                              \
                for (int fc = 0; fc < 4; ++fc) {                               \
                    VLD[fc][0] = *reinterpret_cast<const f16x8*>(vs + (size_t)fc * 16 * 4096); \
                    VLD[fc][1] = *reinterpret_cast<const f16x8*>(vs + (size_t)fc * 16 * 4096 + 32); \
                }                                                              \
            }                                                                  \
            if ((IT) >= 1) {                                                   \
                int pp = ((IT) - 1) & 1;                                       \
                if (Rflag[pp][0] | Rflag[pp][1]) {                             \
                    _Pragma("unroll")                                          \
                    for (int fn = 0; fn < 4; ++fn) {                           \
                        f32x4 rv = *reinterpret_cast<const f32x4*>(&Rrow[pp][fn * 16 + lg * 4]); \
                        _Pragma("unroll")                                      \
                        for (int fc = 0; fc < 4; ++fc)                         \
                            for (int e = 0; e < 4; ++e) acc[fn][fc][e] *= rv[e]; \
                    }                                                          \
                }                                                              \
                __builtin_amdgcn_s_setprio(1);                                 \
                _Pragma("unroll")                                              \
                for (int fn = 0; fn < 4; ++fn) {                               \
                    f16x8 af0 = *reinterpret_cast<const f16x8*>(&Pl[pp][fn * 16 + li][lg * 8]); \
                    f16x8 af1 = *reinterpret_cast<const f16x8*>(&Pl[pp][fn * 16 + li][32 + lg * 8]); \
                    _Pragma("unroll")                                          \
                    for (int fc = 0; fc < 4; ++fc) {                           \
                        acc[fn][fc] = MFMA16(af0, VCON[fc][0], acc[fn][fc]);   \
                        acc[fn][fc] = MFMA16(af1, VCON[fc][1], acc[fn][fc]);   \
                    }                                                          \
                }                                                              \
                __builtin_amdgcn_s_setprio(0);                                 \
            }                                                                  \
            __syncthreads();                                                   \
        }

        for (int it2 = 0; it2 <= 64; it2 += 2) {
            PVBODY(it2, vB, vA)
            if (it2 + 1 <= 64) PVBODY(it2 + 1, vA, vB)
        }
#undef PVBODY

        // epilogue: divide by L, store out[b][c][n]
        float* ob = out + (size_t)b * 512 * 4096;
#pragma unroll
        for (int fn = 0; fn < 4; ++fn) {
            f32x4 lv = *reinterpret_cast<const f32x4*>(&Lrow[fn * 16 + lg * 4]);
            f32x4 linv;
#pragma unroll
            for (int e = 0; e < 4; ++e) linv[e] = 1.f / lv[e];
#pragma unroll
            for (int fc = 0; fc < 4; ++fc) {
                int c = c0 + fc * 16 + li;
                f32x4 o4;
#pragma unroll
                for (int e = 0; e < 4; ++e) o4[e] = acc[fn][fc][e] * linv[e];
                *reinterpret_cast<f32x4*>(ob + (size_t)c * 4096 + n0 + fn * 16 + lg * 4) = o4;
            }
        }
    }
}

// ---------------------------------------------------------------------------
extern "C" void kernel_launch(void* const* d_in, const int* in_sizes, int n_in,
                              void* d_out, int out_size, void* d_ws, size_t ws_size,
                              hipStream_t stream)
{
    const float* content = (const float*)d_in[0];
    const float* style   = (const float*)d_in[1];
    const float* Wq = (const float*)d_in[2];
    const float* bq = (const float*)d_in[3];
    const float* Wk = (const float*)d_in[4];
    const float* bk = (const float*)d_in[5];
    const float* Wv = (const float*)d_in[6];
    const float* bv = (const float*)d_in[7];
    float* out = (float*)d_out;

    const size_t TEN = (size_t)4 * 4096 * 512;
    f16* Qt = (f16*)d_ws;
    f16* Kt = Qt + TEN;
    f16* Vc = Kt + TEN;
    float* mu = (float*)(Vc + TEN);
    float* rs = mu + 4096;
    f16* Wh = (f16*)(rs + 4096);             // 3 x 512 x 512 f16 = 1.5 MB

    hipLaunchKernelGGL(stats_kernel, dim3(4096), dim3(256), 0, stream,
                       content, style, mu, rs);
    hipLaunchKernelGGL(wcvt_kernel, dim3(32, 3), dim3(256), 0, stream,
                       Wq, Wk, Wv, Wh);
    hipLaunchKernelGGL(qkv_kernel, dim3(64, 12), dim3(512), 0, stream,
                       content, style, Wh, bq, bk, bv, mu, rs, Qt, Kt, Vc);
    hipLaunchKernelGGL(attn_kernel, dim3(256), dim3(640), 0, stream,
                       Qt, Kt, Vc, out);
}

// Round 11
// 265.504 us; speedup vs baseline: 1.7288x; 1.7288x over previous
//
#include <hip/hip_runtime.h>

typedef _Float16 f16;
typedef _Float16 f16x4 __attribute__((ext_vector_type(4)));
typedef _Float16 f16x8 __attribute__((ext_vector_type(8)));
typedef float f32x4 __attribute__((ext_vector_type(4)));

#define MFMA16(a, b, c) __builtin_amdgcn_mfma_f32_16x16x32_f16(a, b, c, 0, 0, 0)

// ---------------- Kernel 1: per-(tensor,b,c) mean / inv-std ----------------
__global__ __launch_bounds__(256) void stats_kernel(
    const float* __restrict__ content, const float* __restrict__ style,
    float* __restrict__ mu, float* __restrict__ rs)
{
    int bid = blockIdx.x;            // tensor*2048 + b*512 + c
    int tensor = bid >> 11;
    int row = bid & 2047;
    const float* src = (tensor ? style : content) + (size_t)row * 4096;
    int t = threadIdx.x;
    float s = 0.f, ss = 0.f;
    for (int i = t; i < 1024; i += 256) {
        float4 v = reinterpret_cast<const float4*>(src)[i];
        s  += v.x + v.y + v.z + v.w;
        ss += v.x * v.x + v.y * v.y + v.z * v.z + v.w * v.w;
    }
    for (int off = 32; off > 0; off >>= 1) {
        s  += __shfl_down(s, off);
        ss += __shfl_down(ss, off);
    }
    __shared__ float sb[4], ssb[4];
    int wv = t >> 6;
    if ((t & 63) == 0) { sb[wv] = s; ssb[wv] = ss; }
    __syncthreads();
    if (t == 0) {
        float S  = sb[0] + sb[1] + sb[2] + sb[3];
        float SS = ssb[0] + ssb[1] + ssb[2] + ssb[3];
        float m  = S * (1.f / 4096.f);
        float var = (SS - 4096.f * m * m) * (1.f / 4095.f);
        mu[bid] = m;
        rs[bid] = rsqrtf(var + 1e-5f);
    }
}

// ---------------- Kernel 1b: W -> f16 one-shot conversion ------------------
__global__ __launch_bounds__(256) void wcvt_kernel(
    const float* __restrict__ Wq, const float* __restrict__ Wk,
    const float* __restrict__ Wv, f16* __restrict__ Wh)
{
    int p = blockIdx.y;
    const float* W = (p == 0 ? Wq : (p == 1 ? Wk : Wv));
    f16* dst = Wh + (size_t)p * 262144;
    int base = blockIdx.x * 256 + threadIdx.x;
#pragma unroll
    for (int i = 0; i < 8; ++i) {
        int e4 = i * 8192 + base;
        float4 v = reinterpret_cast<const float4*>(W)[e4];
        f16x4 pk;
        pk[0] = (f16)v.x; pk[1] = (f16)v.y; pk[2] = (f16)v.z; pk[3] = (f16)v.w;
        reinterpret_cast<f16x4*>(dst)[e4] = pk;
    }
}

// ---------------- Kernel 2: fused norm + 1x1-conv (Q,K,V), X-resident ------
__global__ __launch_bounds__(512, 3) void qkv_kernel(
    const float* __restrict__ content, const float* __restrict__ style,
    const f16* __restrict__ Wh,
    const float* __restrict__ bq, const float* __restrict__ bk,
    const float* __restrict__ bv,
    const float* __restrict__ mu, const float* __restrict__ rs,
    f16* __restrict__ Qt, f16* __restrict__ Kt, f16* __restrict__ Vc)
{
    int nb = blockIdx.x;
    int y  = blockIdx.y;
    int b = y / 3, p = y % 3;
    int n0 = nb * 64;
    const float* X    = (p == 0 ? content : style) + (size_t)b * 512 * 4096;
    const f16*   Wp   = Wh + (size_t)p * 262144;
    const float* bias = (p == 0 ? bq : (p == 1 ? bk : bv));
    const float* muT  = mu + (p == 0 ? 0 : 2048) + b * 512;
    const float* rsT  = rs + (p == 0 ? 0 : 2048) + b * 512;
    bool norm = (p < 2);

    __shared__ __align__(16) f16 Xt[64][520];

    int t = threadIdx.x;
    int lane = t & 63, w = t >> 6;
    int lg = lane >> 4, li = lane & 15;

#pragma unroll
    for (int i = 0; i < 16; ++i) {
        int c0 = i * 32 + w * 4;
        float x0 = X[(size_t)(c0 + 0) * 4096 + n0 + lane];
        float x1 = X[(size_t)(c0 + 1) * 4096 + n0 + lane];
        float x2 = X[(size_t)(c0 + 2) * 4096 + n0 + lane];
        float x3 = X[(size_t)(c0 + 3) * 4096 + n0 + lane];
        f16x4 pk;
        if (norm) {
            pk[0] = (f16)((x0 - muT[c0 + 0]) * rsT[c0 + 0]);
            pk[1] = (f16)((x1 - muT[c0 + 1]) * rsT[c0 + 1]);
            pk[2] = (f16)((x2 - muT[c0 + 2]) * rsT[c0 + 2]);
            pk[3] = (f16)((x3 - muT[c0 + 3]) * rsT[c0 + 3]);
        } else {
            pk[0] = (f16)x0; pk[1] = (f16)x1; pk[2] = (f16)x2; pk[3] = (f16)x3;
        }
        *reinterpret_cast<f16x4*>(&Xt[lane][c0]) = pk;
    }
    __syncthreads();

    f32x4 acc[4][4];
#pragma unroll
    for (int i = 0; i < 4; ++i)
#pragma unroll
        for (int j = 0; j < 4; ++j)
#pragma unroll
            for (int e = 0; e < 4; ++e) acc[i][j][e] = 0.f;

    const f16* wbase = Wp + (size_t)(w * 64 + li) * 512 + lg * 8;
    for (int kk = 0; kk < 16; ++kk) {
        f16x8 xf[4], wf[4];
#pragma unroll
        for (int jn = 0; jn < 4; ++jn)
            xf[jn] = *reinterpret_cast<const f16x8*>(&Xt[jn * 16 + li][kk * 32 + lg * 8]);
#pragma unroll
        for (int io = 0; io < 4; ++io)
            wf[io] = *reinterpret_cast<const f16x8*>(wbase + (size_t)io * 16 * 512 + kk * 32);
        if (p < 2) {
#pragma unroll
            for (int io = 0; io < 4; ++io)
#pragma unroll
                for (int jn = 0; jn < 4; ++jn)
                    acc[io][jn] = MFMA16(wf[io], xf[jn], acc[io][jn]);
        } else {
#pragma unroll
            for (int jn = 0; jn < 4; ++jn)
#pragma unroll
                for (int io = 0; io < 4; ++io)
                    acc[jn][io] = MFMA16(xf[jn], wf[io], acc[jn][io]);
        }
    }

    if (p < 2) {
        f16* dst = (p == 0 ? Qt : Kt) + (size_t)b * 4096 * 512;
#pragma unroll
        for (int io = 0; io < 4; ++io) {
            int ob = w * 64 + io * 16 + lg * 4;
            float4 bb = *reinterpret_cast<const float4*>(bias + ob);
#pragma unroll
            for (int jn = 0; jn < 4; ++jn) {
                int n = n0 + jn * 16 + li;
                f16x4 pk;
                pk[0] = (f16)(acc[io][jn][0] + bb.x);
                pk[1] = (f16)(acc[io][jn][1] + bb.y);
                pk[2] = (f16)(acc[io][jn][2] + bb.z);
                pk[3] = (f16)(acc[io][jn][3] + bb.w);
                *reinterpret_cast<f16x4*>(dst + (size_t)n * 512 + ob) = pk;
            }
        }
    } else {
#pragma unroll
        for (int io = 0; io < 4; ++io) {
            int o = w * 64 + io * 16 + li;
            float bb = bias[o];
            f16* dst = Vc + ((size_t)b * 512 + o) * 4096;
#pragma unroll
            for (int jn = 0; jn < 4; ++jn) {
                int n = n0 + jn * 16 + lg * 4;
                f16x4 pk;
#pragma unroll
                for (int e = 0; e < 4; ++e) pk[e] = (f16)(acc[jn][io][e] + bb);
                *reinterpret_cast<f16x4*>(dst + n) = pk;
            }
        }
    }
}

// ---------------- Kernel 3: flash attention, 12-wave balanced, KVBLK=64 ----
// R8-proven structure (183 us, 0 bank conflicts) + PV issue-early V dbuf (T14).
// 768 thr = 12 waves; SIMD k hosts waves {k, k+4, k+8} = 1 QK + 2 PV.
__global__ __launch_bounds__(768, 3) void attn_kernel(
    const f16* __restrict__ Qt, const f16* __restrict__ Kt,
    const f16* __restrict__ Vc, float* __restrict__ out)
{
    int bid = blockIdx.x;
    int orig = (bid & 7) * 32 + (bid >> 3);   // XCD chunking
    int b = orig >> 6;
    int n0 = (orig & 63) * 64;

    int t = threadIdx.x;
    int lane = t & 63, w = t >> 6;
    int lg = lane >> 4, li = lane & 15;

    __shared__ __align__(16) f16 Km[2][64][528];   // K dbuf [m][c]
    __shared__ __align__(16) f16 Pl[2][64][68];    // P ping-pong [q][m]
    __shared__ __align__(16) float Rrow[2][64];
    __shared__ __align__(16) float Lrow[64];
    __shared__ int Rflag[2][4];

    const f16* Qb = Qt + (size_t)b * 4096 * 512;
    const f16* Kb = Kt + (size_t)b * 4096 * 512;
    const f16* Vb = Vc + (size_t)b * 512 * 4096;

    if (w < 4) {
        // =============== QK / softmax wave j = w (q-rows n0+j*16..+16) =====
        int j = w;
        f16x8 qf[16];
#pragma unroll
        for (int kk = 0; kk < 16; ++kk)
            qf[kk] = *reinterpret_cast<const f16x8*>(
                Qb + (size_t)(n0 + j * 16 + li) * 512 + kk * 32 + lg * 8);

#define STAGEK(TILE)                                                           \
        {                                                                      \
            int _db = (TILE) & 1;                                              \
            _Pragma("unroll")                                                  \
            for (int r = 0; r < 16; ++r) {                                     \
                const f16* _gs = Kb + ((size_t)(TILE) * 64 + j * 16 + r) * 512 \
                                 + lane * 8;                                   \
                __builtin_amdgcn_global_load_lds(                              \
                    (const __attribute__((address_space(1))) void*)_gs,        \
                    (__attribute__((address_space(3))) void*)&Km[_db][j * 16 + r][0], \
                    16, 0, 0);                                                 \
            }                                                                  \
        }

        STAGEK(0);
        float Mreg = -3.4e38f, Lreg = 0.f;
        __syncthreads();   // prologue: K0 staged (drained by waitcnt+barrier)

        for (int it = 0; it <= 64; ++it) {
            if (it <= 63) {
                int cur = it & 1;
                if (it < 63) STAGEK(it + 1);

                // S^T = K*Q : 4 m-groups, 4 independent 16-deep chains
                f32x4 s[4];
#pragma unroll
                for (int mg = 0; mg < 4; ++mg)
#pragma unroll
                    for (int e = 0; e < 4; ++e) s[mg][e] = 0.f;
                __builtin_amdgcn_s_setprio(1);
#pragma unroll
                for (int kk = 0; kk < 16; ++kk) {
#pragma unroll
                    for (int mg = 0; mg < 4; ++mg) {
                        f16x8 kf = *reinterpret_cast<const f16x8*>(
                            &Km[cur][mg * 16 + li][kk * 32 + lg * 8]);
                        s[mg] = MFMA16(kf, qf[kk], s[mg]);
                    }
                }
                __builtin_amdgcn_s_setprio(0);

                // wave-local online softmax; lane = q-row (li), 16 m-vals
                float mx = s[0][0];
#pragma unroll
                for (int mg = 0; mg < 4; ++mg)
#pragma unroll
                    for (int e = 0; e < 4; ++e) mx = fmaxf(mx, s[mg][e]);
                mx = fmaxf(mx, __shfl_xor(mx, 16));
                mx = fmaxf(mx, __shfl_xor(mx, 32));
                bool needR = (mx - Mreg) > 4.0f;       // defer-max THR=4
                float Mnew = needR ? mx : Mreg;
                float r = needR ? __expf(Mreg - Mnew) : 1.f;
                float p[4][4];
                float sum = 0.f;
#pragma unroll
                for (int mg = 0; mg < 4; ++mg)
#pragma unroll
                    for (int e = 0; e < 4; ++e) {
                        p[mg][e] = __expf(s[mg][e] - Mnew);
                        sum += p[mg][e];
                    }
                sum += __shfl_xor(sum, 16);
                sum += __shfl_xor(sum, 32);
                Lreg = Lreg * r + sum;
                Mreg = Mnew;

                // P write: rows q = j*16+li; cols m = mg*16 + lg*4 + e
#pragma unroll
                for (int mg = 0; mg < 4; ++mg) {
                    f16x4 pk;
#pragma unroll
                    for (int e = 0; e < 4; ++e) pk[e] = (f16)p[mg][e];
                    *reinterpret_cast<f16x4*>(&Pl[cur][j * 16 + li][mg * 16 + lg * 4]) = pk;
                }
                if (lg == 0) Rrow[cur][j * 16 + li] = r;
                int any = __any(needR);
                if (lane == 0) Rflag[cur][j] = any;
                if (it == 63 && lg == 0) Lrow[j * 16 + li] = Lreg;
            }
            __syncthreads();
        }
#undef STAGEK
    } else {
        // =============== PV wave (c-slice 64), issue-early V dbuf ==========
        int pw = w - 4;
        int c0 = pw * 64;
        f32x4 acc[4][4];
#pragma unroll
        for (int fn = 0; fn < 4; ++fn)
#pragma unroll
            for (int fc = 0; fc < 4; ++fc)
#pragma unroll
                for (int e = 0; e < 4; ++e) acc[fn][fc][e] = 0.f;
        f16x8 vA[4][2], vB[4][2];   // V(even it) -> vA, V(odd it) -> vB

        __syncthreads();   // prologue barrier

#define VLOAD(DST, IT)                                                         \
        {                                                                      \
            const f16* vs = Vb + (size_t)(c0 + li) * 4096 + (IT) * 64 + lg * 8;\
            _Pragma("unroll")                                                  \
            for (int fc = 0; fc < 4; ++fc) {                                   \
                DST[fc][0] = *reinterpret_cast<const f16x8*>(vs + (size_t)fc * 16 * 4096);      \
                DST[fc][1] = *reinterpret_cast<const f16x8*>(vs + (size_t)fc * 16 * 4096 + 32); \
            }                                                                  \
        }
#define PVCOMP(VSRC, IT)                                                       \
        {                                                                      \
            int pp = ((IT) - 1) & 1;                                           \
            if (Rflag[pp][0] | Rflag[pp][1] | Rflag[pp][2] | Rflag[pp][3]) {   \
                _Pragma("unroll")                                              \
                for (int fn = 0; fn < 4; ++fn) {                               \
                    f32x4 rv = *reinterpret_cast<const f32x4*>(&Rrow[pp][fn * 16 + lg * 4]); \
                    _Pragma("unroll")                                          \
                    for (int fc = 0; fc < 4; ++fc)                             \
                        for (int e = 0; e < 4; ++e) acc[fn][fc][e] *= rv[e];   \
                }                                                              \
            }                                                                  \
            __builtin_amdgcn_s_setprio(1);                                     \
            _Pragma("unroll")                                                  \
            for (int fn = 0; fn < 4; ++fn) {                                   \
                f16x8 af0 = *reinterpret_cast<const f16x8*>(&Pl[pp][fn * 16 + li][lg * 8]); \
                f16x8 af1 = *reinterpret_cast<const f16x8*>(&Pl[pp][fn * 16 + li][32 + lg * 8]); \
                _Pragma("unroll")                                              \
                for (int fc = 0; fc < 4; ++fc) {                               \
                    acc[fn][fc] = MFMA16(af0, VSRC[fc][0], acc[fn][fc]);       \
                    acc[fn][fc] = MFMA16(af1, VSRC[fc][1], acc[fn][fc]);       \
                }                                                              \
            }                                                                  \
            __builtin_amdgcn_s_setprio(0);                                     \
        }

        // it = 0: load V(0) only
        VLOAD(vA, 0)
        __syncthreads();
        // its 1..63 in pairs: (odd: load vB, compute vA) (even: load vA, compute vB)
        for (int it2 = 1; it2 < 63; it2 += 2) {
            VLOAD(vB, it2)          // V(odd)
            PVCOMP(vA, it2)         // consumes V(it2-1) (even)
            __syncthreads();
            VLOAD(vA, it2 + 1)      // V(even)
            PVCOMP(vB, it2 + 1)     // consumes V(it2) (odd)
            __syncthreads();
        }
        // it = 63: load V(63) (odd -> vB), compute V(62) (even -> vA)
        VLOAD(vB, 63)
        PVCOMP(vA, 63)
        __syncthreads();
        // it = 64: compute V(63) (odd -> vB)
        PVCOMP(vB, 64)
        __syncthreads();
#undef VLOAD
#undef PVCOMP

        // epilogue: divide by L, store out[b][c][n]
        float* ob = out + (size_t)b * 512 * 4096;
#pragma unroll
        for (int fn = 0; fn < 4; ++fn) {
            f32x4 lv = *reinterpret_cast<const f32x4*>(&Lrow[fn * 16 + lg * 4]);
            f32x4 linv;
#pragma unroll
            for (int e = 0; e < 4; ++e) linv[e] = 1.f / lv[e];
#pragma unroll
            for (int fc = 0; fc < 4; ++fc) {
                int c = c0 + fc * 16 + li;
                f32x4 o4;
#pragma unroll
                for (int e = 0; e < 4; ++e) o4[e] = acc[fn][fc][e] * linv[e];
                *reinterpret_cast<f32x4*>(ob + (size_t)c * 4096 + n0 + fn * 16 + lg * 4) = o4;
            }
        }
    }
}

// ---------------------------------------------------------------------------
extern "C" void kernel_launch(void* const* d_in, const int* in_sizes, int n_in,
                              void* d_out, int out_size, void* d_ws, size_t ws_size,
                              hipStream_t stream)
{
    const float* content = (const float*)d_in[0];
    const float* style   = (const float*)d_in[1];
    const float* Wq = (const float*)d_in[2];
    const float* bq = (const float*)d_in[3];
    const float* Wk = (const float*)d_in[4];
    const float* bk = (const float*)d_in[5];
    const float* Wv = (const float*)d_in[6];
    const float* bv = (const float*)d_in[7];
    float* out = (float*)d_out;

    const size_t TEN = (size_t)4 * 4096 * 512;
    f16* Qt = (f16*)d_ws;
    f16* Kt = Qt + TEN;
    f16* Vc = Kt + TEN;
    float* mu = (float*)(Vc + TEN);
    float* rs = mu + 4096;
    f16* Wh = (f16*)(rs + 4096);             // 3 x 512 x 512 f16 = 1.5 MB

    hipLaunchKernelGGL(stats_kernel, dim3(4096), dim3(256), 0, stream,
                       content, style, mu, rs);
    hipLaunchKernelGGL(wcvt_kernel, dim3(32, 3), dim3(256), 0, stream,
                       Wq, Wk, Wv, Wh);
    hipLaunchKernelGGL(qkv_kernel, dim3(64, 12), dim3(512), 0, stream,
                       content, style, Wh, bq, bk, bv, mu, rs, Qt, Kt, Vc);
    hipLaunchKernelGGL(attn_kernel, dim3(256), dim3(768), 0, stream,
                       Qt, Kt, Vc, out);
}

// Round 12
// 250.517 us; speedup vs baseline: 1.8323x; 1.0598x over previous
//
#include <hip/hip_runtime.h>

typedef _Float16 f16;
typedef _Float16 f16x4 __attribute__((ext_vector_type(4)));
typedef _Float16 f16x8 __attribute__((ext_vector_type(8)));
typedef float f32x4 __attribute__((ext_vector_type(4)));

#define MFMA16(a, b, c) __builtin_amdgcn_mfma_f32_16x16x32_f16(a, b, c, 0, 0, 0)

// ---------------- Kernel 1: per-(tensor,b,c) mean / inv-std ----------------
__global__ __launch_bounds__(256) void stats_kernel(
    const float* __restrict__ content, const float* __restrict__ style,
    float* __restrict__ mu, float* __restrict__ rs)
{
    int bid = blockIdx.x;            // tensor*2048 + b*512 + c
    int tensor = bid >> 11;
    int row = bid & 2047;
    const float* src = (tensor ? style : content) + (size_t)row * 4096;
    int t = threadIdx.x;
    float s = 0.f, ss = 0.f;
    for (int i = t; i < 1024; i += 256) {
        float4 v = reinterpret_cast<const float4*>(src)[i];
        s  += v.x + v.y + v.z + v.w;
        ss += v.x * v.x + v.y * v.y + v.z * v.z + v.w * v.w;
    }
    for (int off = 32; off > 0; off >>= 1) {
        s  += __shfl_down(s, off);
        ss += __shfl_down(ss, off);
    }
    __shared__ float sb[4], ssb[4];
    int wv = t >> 6;
    if ((t & 63) == 0) { sb[wv] = s; ssb[wv] = ss; }
    __syncthreads();
    if (t == 0) {
        float S  = sb[0] + sb[1] + sb[2] + sb[3];
        float SS = ssb[0] + ssb[1] + ssb[2] + ssb[3];
        float m  = S * (1.f / 4096.f);
        float var = (SS - 4096.f * m * m) * (1.f / 4095.f);
        mu[bid] = m;
        rs[bid] = rsqrtf(var + 1e-5f);
    }
}

// ---------------- Kernel 1b: W -> f16 one-shot conversion ------------------
__global__ __launch_bounds__(256) void wcvt_kernel(
    const float* __restrict__ Wq, const float* __restrict__ Wk,
    const float* __restrict__ Wv, f16* __restrict__ Wh)
{
    int p = blockIdx.y;
    const float* W = (p == 0 ? Wq : (p == 1 ? Wk : Wv));
    f16* dst = Wh + (size_t)p * 262144;
    int base = blockIdx.x * 256 + threadIdx.x;
#pragma unroll
    for (int i = 0; i < 8; ++i) {
        int e4 = i * 8192 + base;
        float4 v = reinterpret_cast<const float4*>(W)[e4];
        f16x4 pk;
        pk[0] = (f16)v.x; pk[1] = (f16)v.y; pk[2] = (f16)v.z; pk[3] = (f16)v.w;
        reinterpret_cast<f16x4*>(dst)[e4] = pk;
    }
}

// ---------------- Kernel 2: fused norm + 1x1-conv (Q,K,V), X-resident ------
__global__ __launch_bounds__(512, 3) void qkv_kernel(
    const float* __restrict__ content, const float* __restrict__ style,
    const f16* __restrict__ Wh,
    const float* __restrict__ bq, const float* __restrict__ bk,
    const float* __restrict__ bv,
    const float* __restrict__ mu, const float* __restrict__ rs,
    f16* __restrict__ Qt, f16* __restrict__ Kt, f16* __restrict__ Vc)
{
    int nb = blockIdx.x;
    int y  = blockIdx.y;
    int b = y / 3, p = y % 3;
    int n0 = nb * 64;
    const float* X    = (p == 0 ? content : style) + (size_t)b * 512 * 4096;
    const f16*   Wp   = Wh + (size_t)p * 262144;
    const float* bias = (p == 0 ? bq : (p == 1 ? bk : bv));
    const float* muT  = mu + (p == 0 ? 0 : 2048) + b * 512;
    const float* rsT  = rs + (p == 0 ? 0 : 2048) + b * 512;
    bool norm = (p < 2);

    __shared__ __align__(16) f16 Xt[64][520];

    int t = threadIdx.x;
    int lane = t & 63, w = t >> 6;
    int lg = lane >> 4, li = lane & 15;

#pragma unroll
    for (int i = 0; i < 16; ++i) {
        int c0 = i * 32 + w * 4;
        float x0 = X[(size_t)(c0 + 0) * 4096 + n0 + lane];
        float x1 = X[(size_t)(c0 + 1) * 4096 + n0 + lane];
        float x2 = X[(size_t)(c0 + 2) * 4096 + n0 + lane];
        float x3 = X[(size_t)(c0 + 3) * 4096 + n0 + lane];
        f16x4 pk;
        if (norm) {
            pk[0] = (f16)((x0 - muT[c0 + 0]) * rsT[c0 + 0]);
            pk[1] = (f16)((x1 - muT[c0 + 1]) * rsT[c0 + 1]);
            pk[2] = (f16)((x2 - muT[c0 + 2]) * rsT[c0 + 2]);
            pk[3] = (f16)((x3 - muT[c0 + 3]) * rsT[c0 + 3]);
        } else {
            pk[0] = (f16)x0; pk[1] = (f16)x1; pk[2] = (f16)x2; pk[3] = (f16)x3;
        }
        *reinterpret_cast<f16x4*>(&Xt[lane][c0]) = pk;
    }
    __syncthreads();

    f32x4 acc[4][4];
#pragma unroll
    for (int i = 0; i < 4; ++i)
#pragma unroll
        for (int j = 0; j < 4; ++j)
#pragma unroll
            for (int e = 0; e < 4; ++e) acc[i][j][e] = 0.f;

    const f16* wbase = Wp + (size_t)(w * 64 + li) * 512 + lg * 8;
    for (int kk = 0; kk < 16; ++kk) {
        f16x8 xf[4], wf[4];
#pragma unroll
        for (int jn = 0; jn < 4; ++jn)
            xf[jn] = *reinterpret_cast<const f16x8*>(&Xt[jn * 16 + li][kk * 32 + lg * 8]);
#pragma unroll
        for (int io = 0; io < 4; ++io)
            wf[io] = *reinterpret_cast<const f16x8*>(wbase + (size_t)io * 16 * 512 + kk * 32);
        if (p < 2) {
#pragma unroll
            for (int io = 0; io < 4; ++io)
#pragma unroll
                for (int jn = 0; jn < 4; ++jn)
                    acc[io][jn] = MFMA16(wf[io], xf[jn], acc[io][jn]);
        } else {
#pragma unroll
            for (int jn = 0; jn < 4; ++jn)
#pragma unroll
                for (int io = 0; io < 4; ++io)
                    acc[jn][io] = MFMA16(xf[jn], wf[io], acc[jn][io]);
        }
    }

    if (p < 2) {
        f16* dst = (p == 0 ? Qt : Kt) + (size_t)b * 4096 * 512;
#pragma unroll
        for (int io = 0; io < 4; ++io) {
            int ob = w * 64 + io * 16 + lg * 4;
            float4 bb = *reinterpret_cast<const float4*>(bias + ob);
#pragma unroll
            for (int jn = 0; jn < 4; ++jn) {
                int n = n0 + jn * 16 + li;
                f16x4 pk;
                pk[0] = (f16)(acc[io][jn][0] + bb.x);
                pk[1] = (f16)(acc[io][jn][1] + bb.y);
                pk[2] = (f16)(acc[io][jn][2] + bb.z);
                pk[3] = (f16)(acc[io][jn][3] + bb.w);
                *reinterpret_cast<f16x4*>(dst + (size_t)n * 512 + ob) = pk;
            }
        }
    } else {
#pragma unroll
        for (int io = 0; io < 4; ++io) {
            int o = w * 64 + io * 16 + li;
            float bb = bias[o];
            f16* dst = Vc + ((size_t)b * 512 + o) * 4096;
#pragma unroll
            for (int jn = 0; jn < 4; ++jn) {
                int n = n0 + jn * 16 + lg * 4;
                f16x4 pk;
#pragma unroll
                for (int e = 0; e < 4; ++e) pk[e] = (f16)(acc[jn][io][e] + bb);
                *reinterpret_cast<f16x4*>(dst + n) = pk;
            }
        }
    }
}

// ---------------- Kernel 3: flash attention, 12-wave balanced, KVBLK=64 ----
// EXACT R8 structure (measured 183 us, 0 bank conflicts).
// 768 thr = 12 waves; SIMD k hosts waves {k, k+4, k+8} = 1 QK + 2 PV.
__global__ __launch_bounds__(768, 3) void attn_kernel(
    const f16* __restrict__ Qt, const f16* __restrict__ Kt,
    const f16* __restrict__ Vc, float* __restrict__ out)
{
    int bid = blockIdx.x;
    int orig = (bid & 7) * 32 + (bid >> 3);   // XCD chunking
    int b = orig >> 6;
    int n0 = (orig & 63) * 64;

    int t = threadIdx.x;
    int lane = t & 63, w = t >> 6;
    int lg = lane >> 4, li = lane & 15;

    __shared__ __align__(16) f16 Km[2][64][528];   // K dbuf [m][c]
    __shared__ __align__(16) f16 Pl[2][64][68];    // P ping-pong [q][m]
    __shared__ __align__(16) float Rrow[2][64];
    __shared__ __align__(16) float Lrow[64];
    __shared__ int Rflag[2][4];

    const f16* Qb = Qt + (size_t)b * 4096 * 512;
    const f16* Kb = Kt + (size_t)b * 4096 * 512;
    const f16* Vb = Vc + (size_t)b * 512 * 4096;

    if (w < 4) {
        int j = w;
        f16x8 qf[16];
#pragma unroll
        for (int kk = 0; kk < 16; ++kk)
            qf[kk] = *reinterpret_cast<const f16x8*>(
                Qb + (size_t)(n0 + j * 16 + li) * 512 + kk * 32 + lg * 8);

#define STAGEK(TILE)                                                           \
        {                                                                      \
            int _db = (TILE) & 1;                                              \
            _Pragma("unroll")                                                  \
            for (int r = 0; r < 16; ++r) {                                     \
                const f16* _gs = Kb + ((size_t)(TILE) * 64 + j * 16 + r) * 512 \
                                 + lane * 8;                                   \
                __builtin_amdgcn_global_load_lds(                              \
                    (const __attribute__((address_space(1))) void*)_gs,        \
                    (__attribute__((address_space(3))) void*)&Km[_db][j * 16 + r][0], \
                    16, 0, 0);                                                 \
            }                                                                  \
        }

        STAGEK(0);
        float Mreg = -3.4e38f, Lreg = 0.f;
        __syncthreads();

        for (int it = 0; it <= 64; ++it) {
            if (it <= 63) {
                int cur = it & 1;
                if (it < 63) STAGEK(it + 1);

                f32x4 s[4];
#pragma unroll
                for (int mg = 0; mg < 4; ++mg)
#pragma unroll
                    for (int e = 0; e < 4; ++e) s[mg][e] = 0.f;
                __builtin_amdgcn_s_setprio(1);
#pragma unroll
                for (int kk = 0; kk < 16; ++kk) {
#pragma unroll
                    for (int mg = 0; mg < 4; ++mg) {
                        f16x8 kf = *reinterpret_cast<const f16x8*>(
                            &Km[cur][mg * 16 + li][kk * 32 + lg * 8]);
                        s[mg] = MFMA16(kf, qf[kk], s[mg]);
                    }
                }
                __builtin_amdgcn_s_setprio(0);

                float mx = s[0][0];
#pragma unroll
                for (int mg = 0; mg < 4; ++mg)
#pragma unroll
                    for (int e = 0; e < 4; ++e) mx = fmaxf(mx, s[mg][e]);
                mx = fmaxf(mx, __shfl_xor(mx, 16));
                mx = fmaxf(mx, __shfl_xor(mx, 32));
                bool needR = (mx - Mreg) > 4.0f;       // defer-max THR=4
                float Mnew = needR ? mx : Mreg;
                float r = needR ? __expf(Mreg - Mnew) : 1.f;
                float p[4][4];
                float sum = 0.f;
#pragma unroll
                for (int mg = 0; mg < 4; ++mg)
#pragma unroll
                    for (int e = 0; e < 4; ++e) {
                        p[mg][e] = __expf(s[mg][e] - Mnew);
                        sum += p[mg][e];
                    }
                sum += __shfl_xor(sum, 16);
                sum += __shfl_xor(sum, 32);
                Lreg = Lreg * r + sum;
                Mreg = Mnew;

#pragma unroll
                for (int mg = 0; mg < 4; ++mg) {
                    f16x4 pk;
#pragma unroll
                    for (int e = 0; e < 4; ++e) pk[e] = (f16)p[mg][e];
                    *reinterpret_cast<f16x4*>(&Pl[cur][j * 16 + li][mg * 16 + lg * 4]) = pk;
                }
                if (lg == 0) Rrow[cur][j * 16 + li] = r;
                int any = __any(needR);
                if (lane == 0) Rflag[cur][j] = any;
                if (it == 63 && lg == 0) Lrow[j * 16 + li] = Lreg;
            }
            __syncthreads();
        }
#undef STAGEK
    } else {
        int pw = w - 4;
        int c0 = pw * 64;
        f32x4 acc[4][4];
#pragma unroll
        for (int fn = 0; fn < 4; ++fn)
#pragma unroll
            for (int fc = 0; fc < 4; ++fc)
#pragma unroll
                for (int e = 0; e < 4; ++e) acc[fn][fc][e] = 0.f;
        f16x8 vfr[4][2];

        __syncthreads();

        for (int it = 0; it <= 64; ++it) {
            if (it >= 1) {
                int pp = (it - 1) & 1;
                if (Rflag[pp][0] | Rflag[pp][1] | Rflag[pp][2] | Rflag[pp][3]) {
#pragma unroll
                    for (int fn = 0; fn < 4; ++fn) {
                        f32x4 rv = *reinterpret_cast<const f32x4*>(&Rrow[pp][fn * 16 + lg * 4]);
#pragma unroll
                        for (int fc = 0; fc < 4; ++fc)
#pragma unroll
                            for (int e = 0; e < 4; ++e) acc[fn][fc][e] *= rv[e];
                    }
                }
                __builtin_amdgcn_s_setprio(1);
#pragma unroll
                for (int fn = 0; fn < 4; ++fn) {
                    f16x8 af0 = *reinterpret_cast<const f16x8*>(&Pl[pp][fn * 16 + li][lg * 8]);
                    f16x8 af1 = *reinterpret_cast<const f16x8*>(&Pl[pp][fn * 16 + li][32 + lg * 8]);
#pragma unroll
                    for (int fc = 0; fc < 4; ++fc) {
                        acc[fn][fc] = MFMA16(af0, vfr[fc][0], acc[fn][fc]);
                        acc[fn][fc] = MFMA16(af1, vfr[fc][1], acc[fn][fc]);
                    }
                }
                __builtin_amdgcn_s_setprio(0);
            }
            if (it <= 63) {
                const f16* vs = Vb + (size_t)(c0 + li) * 4096 + it * 64 + lg * 8;
#pragma unroll
                for (int fc = 0; fc < 4; ++fc) {
                    vfr[fc][0] = *reinterpret_cast<const f16x8*>(vs + (size_t)fc * 16 * 4096);
                    vfr[fc][1] = *reinterpret_cast<const f16x8*>(vs + (size_t)fc * 16 * 4096 + 32);
                }
            }
            __syncthreads();
        }

        float* ob = out + (size_t)b * 512 * 4096;
#pragma unroll
        for (int fn = 0; fn < 4; ++fn) {
            f32x4 lv = *reinterpret_cast<const f32x4*>(&Lrow[fn * 16 + lg * 4]);
            f32x4 linv;
#pragma unroll
            for (int e = 0; e < 4; ++e) linv[e] = 1.f / lv[e];
#pragma unroll
            for (int fc = 0; fc < 4; ++fc) {
                int c = c0 + fc * 16 + li;
                f32x4 o4;
#pragma unroll
                for (int e = 0; e < 4; ++e) o4[e] = acc[fn][fc][e] * linv[e];
                *reinterpret_cast<f32x4*>(ob + (size_t)c * 4096 + n0 + fn * 16 + lg * 4) = o4;
            }
        }
    }
}

// ---------------------------------------------------------------------------
extern "C" void kernel_launch(void* const* d_in, const int* in_sizes, int n_in,
                              void* d_out, int out_size, void* d_ws, size_t ws_size,
                              hipStream_t stream)
{
    const float* content = (const float*)d_in[0];
    const float* style   = (const float*)d_in[1];
    const float* Wq = (const float*)d_in[2];
    const float* bq = (const float*)d_in[3];
    const float* Wk = (const float*)d_in[4];
    const float* bk = (const float*)d_in[5];
    const float* Wv = (const float*)d_in[6];
    const float* bv = (const float*)d_in[7];
    float* out = (float*)d_out;

    const size_t TEN = (size_t)4 * 4096 * 512;
    f16* Qt = (f16*)d_ws;
    f16* Kt = Qt + TEN;
    f16* Vc = Kt + TEN;
    float* mu = (float*)(Vc + TEN);
    float* rs = mu + 4096;
    f16* Wh = (f16*)(rs + 4096);             // 3 x 512 x 512 f16 = 1.5 MB

    hipLaunchKernelGGL(stats_kernel, dim3(4096), dim3(256), 0, stream,
                       content, style, mu, rs);
    hipLaunchKernelGGL(wcvt_kernel, dim3(32, 3), dim3(256), 0, stream,
                       Wq, Wk, Wv, Wh);
    hipLaunchKernelGGL(qkv_kernel, dim3(64, 12), dim3(512), 0, stream,
                       content, style, Wh, bq, bk, bv, mu, rs, Qt, Kt, Vc);
    hipLaunchKernelGGL(attn_kernel, dim3(256), dim3(768), 0, stream,
                       Qt, Kt, Vc, out);
}